// Round 1
// baseline (440.124 us; speedup 1.0000x reference)
//
#include <hip/hip_runtime.h>

#define EPT 16          // contiguous edges per thread
#define TBL 450         // NUM_RELS * 9

__global__ void zero_kernel(float* __restrict__ out, int n) {
    int i = blockIdx.x * blockDim.x + threadIdx.x;
    if (i < n) out[i] = 0.0f;
}

__launch_bounds__(256)
__global__ void edge_score_kernel(const int* __restrict__ node_type,
                                  const int* __restrict__ edge_type,
                                  const int* __restrict__ esrc,
                                  const int* __restrict__ edst,
                                  const int* __restrict__ edge_batch,
                                  const float* __restrict__ w,
                                  float* __restrict__ out,
                                  long E) {
    __shared__ float lw[TBL];
    for (int i = threadIdx.x; i < TBL; i += 256) lw[i] = w[i];
    __syncthreads();

    long tid  = (long)blockIdx.x * blockDim.x + threadIdx.x;
    long base = tid * EPT;

    float acc   = 0.0f;
    int   cur_b = -1;
    int   nflush = 0;   // interior segment flushes (graph boundary inside this thread)

    if (base < E) {
        #pragma unroll
        for (int j = 0; j < EPT / 4; ++j) {
            long e = base + (long)j * 4;
            if (e + 3 < E) {
                int4 et = *reinterpret_cast<const int4*>(edge_type + e);
                int4 sv = *reinterpret_cast<const int4*>(esrc + e);
                int4 dv = *reinterpret_cast<const int4*>(edst + e);
                int4 bv = *reinterpret_cast<const int4*>(edge_batch + e);
                int ets[4] = {et.x, et.y, et.z, et.w};
                int svs[4] = {sv.x, sv.y, sv.z, sv.w};
                int dvs[4] = {dv.x, dv.y, dv.z, dv.w};
                int bvs[4] = {bv.x, bv.y, bv.z, bv.w};
                #pragma unroll
                for (int k = 0; k < 4; ++k) {
                    int enc = ets[k] * 9 + node_type[svs[k]] * 3 + node_type[dvs[k]];
                    float v = lw[enc];
                    int b = bvs[k];
                    if (b != cur_b) {
                        if (cur_b >= 0) { atomicAdd(&out[cur_b], acc); ++nflush; }
                        cur_b = b;
                        acc = 0.0f;
                    }
                    acc += v;
                }
            } else {
                // scalar tail (never taken for E = 2^24, kept for generality)
                for (long ee = e; ee < E; ++ee) {
                    int enc = edge_type[ee] * 9 + node_type[esrc[ee]] * 3 + node_type[edst[ee]];
                    float v = lw[enc];
                    int b = edge_batch[ee];
                    if (b != cur_b) {
                        if (cur_b >= 0) { atomicAdd(&out[cur_b], acc); ++nflush; }
                        cur_b = b;
                        acc = 0.0f;
                    }
                    acc += v;
                }
            }
        }
    }

    // Wave-level combine of the final segment.
    // Fast path: all 64 lanes processed exactly one segment of the same graph
    // (common case: edge_batch sorted, ~4096 edges/graph vs 1024 edges/wave).
    int  b0  = __shfl(cur_b, 0);
    bool uni = (nflush == 0) && (cur_b == b0) && (cur_b >= 0);
    if (__all(uni)) {
        #pragma unroll
        for (int off = 32; off >= 1; off >>= 1)
            acc += __shfl_down(acc, off);
        if ((threadIdx.x & 63) == 0)
            atomicAdd(&out[b0], acc);
    } else if (cur_b >= 0) {
        atomicAdd(&out[cur_b], acc);
    }
}

extern "C" void kernel_launch(void* const* d_in, const int* in_sizes, int n_in,
                              void* d_out, int out_size, void* d_ws, size_t ws_size,
                              hipStream_t stream) {
    const int*   node_type  = (const int*)d_in[0];
    const int*   edge_type  = (const int*)d_in[1];
    const int*   edge_index = (const int*)d_in[2];   // [2, E]: src then dst
    const int*   edge_batch = (const int*)d_in[3];
    const float* w          = (const float*)d_in[4];
    float* out = (float*)d_out;

    long E = in_sizes[1];

    // d_out is poisoned (0xAA) once and never re-poisoned between replays;
    // we accumulate with atomics, so zero it at the start of every launch.
    zero_kernel<<<(out_size + 255) / 256, 256, 0, stream>>>(out, out_size);

    long threads_needed = (E + EPT - 1) / EPT;
    int  blocks = (int)((threads_needed + 255) / 256);
    edge_score_kernel<<<blocks, 256, 0, stream>>>(
        node_type, edge_type, edge_index, edge_index + E, edge_batch, w, out, E);
}

// Round 2
// 269.590 us; speedup vs baseline: 1.6326x; 1.6326x over previous
//
#include <hip/hip_runtime.h>

#define TBL 450                 // NUM_RELS * 9
typedef int v4i __attribute__((ext_vector_type(4)));

__global__ void zero_kernel(float* __restrict__ out, int n) {
    int i = blockIdx.x * blockDim.x + threadIdx.x;
    if (i < n) out[i] = 0.0f;
}

// Pack node_type (values 0..2) into 2 bits/node: 16 nodes per uint32.
__global__ void pack_nt_kernel(const int* __restrict__ nt,
                               unsigned int* __restrict__ packed,
                               int nwords, int N) {
    int i = blockIdx.x * blockDim.x + threadIdx.x;
    if (i >= nwords) return;
    unsigned int word = 0;
    int base = i * 16;
    if (base + 16 <= N) {
        #pragma unroll
        for (int j = 0; j < 4; ++j) {
            int4 v = *reinterpret_cast<const int4*>(nt + base + j * 4);
            word |= (unsigned)(v.x & 3) << (2 * (j * 4 + 0));
            word |= (unsigned)(v.y & 3) << (2 * (j * 4 + 1));
            word |= (unsigned)(v.z & 3) << (2 * (j * 4 + 2));
            word |= (unsigned)(v.w & 3) << (2 * (j * 4 + 3));
        }
    } else {
        for (int j = 0; base + j < N; ++j)
            word |= (unsigned)(nt[base + j] & 3) << (2 * j);
    }
    packed[i] = word;
}

// Each wave handles 4096 contiguous edges: 16 iterations x (64 lanes x int4).
// Streams are wave-coalesced (1 KB per load instruction) and nontemporal;
// node-type gathers hit the 256 KB packed table (L2-resident).
template <bool PACKED>
__launch_bounds__(256)
__global__ void edge_score_kernel(const unsigned int* __restrict__ pnt,
                                  const int* __restrict__ node_type,
                                  const int* __restrict__ edge_type,
                                  const int* __restrict__ esrc,
                                  const int* __restrict__ edst,
                                  const int* __restrict__ edge_batch,
                                  const float* __restrict__ w,
                                  float* __restrict__ out,
                                  long E, long waves_total) {
    __shared__ float lw[TBL];
    for (int i = threadIdx.x; i < TBL; i += 256) lw[i] = w[i];
    __syncthreads();

    long gtid = (long)blockIdx.x * blockDim.x + threadIdx.x;
    long wave = gtid >> 6;
    int  lane = threadIdx.x & 63;
    if (wave >= waves_total) return;

    long base_w = wave * 4096;
    float acc = 0.0f;
    int   cur_b = -1;

    #pragma unroll 4
    for (int it = 0; it < 16; ++it) {
        long e = base_w + (long)it * 256 + lane * 4;
        if (e + 3 < E) {
            v4i et = __builtin_nontemporal_load(reinterpret_cast<const v4i*>(edge_type + e));
            v4i sv = __builtin_nontemporal_load(reinterpret_cast<const v4i*>(esrc + e));
            v4i dv = __builtin_nontemporal_load(reinterpret_cast<const v4i*>(edst + e));
            v4i bv = __builtin_nontemporal_load(reinterpret_cast<const v4i*>(edge_batch + e));
            #pragma unroll
            for (int k = 0; k < 4; ++k) {
                int s = sv[k], d = dv[k];
                int nts, ntd;
                if (PACKED) {
                    nts = (pnt[(unsigned)s >> 4] >> (((unsigned)s & 15u) << 1)) & 3;
                    ntd = (pnt[(unsigned)d >> 4] >> (((unsigned)d & 15u) << 1)) & 3;
                } else {
                    nts = node_type[s];
                    ntd = node_type[d];
                }
                int enc = et[k] * 9 + nts * 3 + ntd;
                float v = lw[enc];
                int b = bv[k];
                if (b != cur_b) {
                    if (cur_b >= 0) atomicAdd(&out[cur_b], acc);
                    cur_b = b;
                    acc = 0.0f;
                }
                acc += v;
            }
        } else {
            for (long ee = e; ee < E && ee < e + 4; ++ee) {
                int s = esrc[ee], d = edst[ee];
                int nts, ntd;
                if (PACKED) {
                    nts = (pnt[(unsigned)s >> 4] >> (((unsigned)s & 15u) << 1)) & 3;
                    ntd = (pnt[(unsigned)d >> 4] >> (((unsigned)d & 15u) << 1)) & 3;
                } else {
                    nts = node_type[s];
                    ntd = node_type[d];
                }
                int enc = edge_type[ee] * 9 + nts * 3 + ntd;
                float v = lw[enc];
                int b = edge_batch[ee];
                if (b != cur_b) {
                    if (cur_b >= 0) atomicAdd(&out[cur_b], acc);
                    cur_b = b;
                    acc = 0.0f;
                }
                acc += v;
            }
        }
    }
    if (cur_b >= 0) atomicAdd(&out[cur_b], acc);
}

extern "C" void kernel_launch(void* const* d_in, const int* in_sizes, int n_in,
                              void* d_out, int out_size, void* d_ws, size_t ws_size,
                              hipStream_t stream) {
    const int*   node_type  = (const int*)d_in[0];
    const int*   edge_type  = (const int*)d_in[1];
    const int*   edge_index = (const int*)d_in[2];   // [2, E]: src then dst
    const int*   edge_batch = (const int*)d_in[3];
    const float* w          = (const float*)d_in[4];
    float* out = (float*)d_out;

    long N = in_sizes[0];
    long E = in_sizes[1];

    // d_out is poisoned once and never re-poisoned between replays; we
    // accumulate with atomics, so zero it at the start of every launch.
    zero_kernel<<<(out_size + 255) / 256, 256, 0, stream>>>(out, out_size);

    long waves_total = (E + 4095) / 4096;
    long threads     = waves_total * 64;
    int  blocks      = (int)((threads + 255) / 256);

    int nwords = (int)((N + 15) / 16);
    bool have_ws = (ws_size >= (size_t)nwords * 4);

    if (have_ws) {
        unsigned int* pnt = (unsigned int*)d_ws;
        pack_nt_kernel<<<(nwords + 255) / 256, 256, 0, stream>>>(node_type, pnt, nwords, (int)N);
        edge_score_kernel<true><<<blocks, 256, 0, stream>>>(
            pnt, node_type, edge_type, edge_index, edge_index + E, edge_batch, w, out,
            E, waves_total);
    } else {
        edge_score_kernel<false><<<blocks, 256, 0, stream>>>(
            nullptr, node_type, edge_type, edge_index, edge_index + E, edge_batch, w, out,
            E, waves_total);
    }
}

// Round 3
// 251.555 us; speedup vs baseline: 1.7496x; 1.0717x over previous
//
#include <hip/hip_runtime.h>

#define TBL 450                 // NUM_RELS * 9
typedef int v4i __attribute__((ext_vector_type(4)));

__global__ void zero_kernel(float* __restrict__ out, int n) {
    int i = blockIdx.x * blockDim.x + threadIdx.x;
    if (i < n) out[i] = 0.0f;
}

// Pack node_type (values 0..2) into 2 bits/node: 16 nodes per uint32 (256 KB).
__global__ void pack_nt_kernel(const int* __restrict__ nt,
                               unsigned int* __restrict__ packed,
                               int nwords, int N) {
    int i = blockIdx.x * blockDim.x + threadIdx.x;
    if (i >= nwords) return;
    unsigned int word = 0;
    int base = i * 16;
    if (base + 16 <= N) {
        #pragma unroll
        for (int j = 0; j < 4; ++j) {
            int4 v = *reinterpret_cast<const int4*>(nt + base + j * 4);
            word |= (unsigned)(v.x & 3) << (2 * (j * 4 + 0));
            word |= (unsigned)(v.y & 3) << (2 * (j * 4 + 1));
            word |= (unsigned)(v.z & 3) << (2 * (j * 4 + 2));
            word |= (unsigned)(v.w & 3) << (2 * (j * 4 + 3));
        }
    } else {
        for (int j = 0; base + j < N; ++j)
            word |= (unsigned)(nt[base + j] & 3) << (2 * j);
    }
    packed[i] = word;
}

// One wave = 256 contiguous edges (lane*4, one int4 per stream).
// All stream loads + all 8 gathers issued at a single dependence level;
// tiny per-wave body + huge grid (65536 waves) maximizes outstanding
// gather requests per CU. Wave-uniform fast path -> 1 atomic per wave.
template <bool PACKED>
__launch_bounds__(256, 8)
__global__ void edge_score_kernel(const unsigned int* __restrict__ pnt,
                                  const int* __restrict__ node_type,
                                  const int* __restrict__ edge_type,
                                  const int* __restrict__ esrc,
                                  const int* __restrict__ edst,
                                  const int* __restrict__ edge_batch,
                                  const float* __restrict__ w,
                                  float* __restrict__ out,
                                  long E, long waves_total) {
    __shared__ float lw[TBL];
    for (int i = threadIdx.x; i < TBL; i += 256) lw[i] = w[i];
    __syncthreads();

    long gtid = (long)blockIdx.x * blockDim.x + threadIdx.x;
    long wave = gtid >> 6;
    int  lane = threadIdx.x & 63;
    if (wave >= waves_total) return;

    long e = wave * 256 + (long)lane * 4;

    if (e + 3 < E) {
        // ---- full vector path ----
        v4i et = __builtin_nontemporal_load(reinterpret_cast<const v4i*>(edge_type + e));
        v4i sv = __builtin_nontemporal_load(reinterpret_cast<const v4i*>(esrc + e));
        v4i dv = __builtin_nontemporal_load(reinterpret_cast<const v4i*>(edst + e));
        v4i bv = __builtin_nontemporal_load(reinterpret_cast<const v4i*>(edge_batch + e));

        int nts[4], ntd[4];
        #pragma unroll
        for (int k = 0; k < 4; ++k) {
            int s = sv[k], d = dv[k];
            if (PACKED) {
                nts[k] = (pnt[(unsigned)s >> 4] >> (((unsigned)s & 15u) << 1)) & 3;
                ntd[k] = (pnt[(unsigned)d >> 4] >> (((unsigned)d & 15u) << 1)) & 3;
            } else {
                nts[k] = node_type[s];
                ntd[k] = node_type[d];
            }
        }
        float v[4];
        #pragma unroll
        for (int k = 0; k < 4; ++k)
            v[k] = lw[et[k] * 9 + nts[k] * 3 + ntd[k]];

        // Wave-uniform fast path: edge_batch sorted; a 256-edge window is
        // single-graph ~94% of the time.
        int  b0      = bv[0];
        bool lane_u  = (bv[0] == bv[3]);          // sorted => all 4 equal
        int  wb0     = __shfl(b0, 0);
        if (__all(lane_u && (b0 == wb0))) {
            float s = (v[0] + v[1]) + (v[2] + v[3]);
            #pragma unroll
            for (int off = 32; off >= 1; off >>= 1)
                s += __shfl_down(s, off);
            if (lane == 0) atomicAdd(&out[wb0], s);
        } else {
            float acc = v[0];
            int   cur = bv[0];
            #pragma unroll
            for (int k = 1; k < 4; ++k) {
                if (bv[k] != cur) { atomicAdd(&out[cur], acc); cur = bv[k]; acc = 0.0f; }
                acc += v[k];
            }
            atomicAdd(&out[cur], acc);
        }
    } else {
        // scalar tail (never taken for E = 2^24)
        float acc = 0.0f;
        int   cur = -1;
        for (long ee = e; ee < E && ee < e + 4; ++ee) {
            int s = esrc[ee], d = edst[ee];
            int a, b;
            if (PACKED) {
                a = (pnt[(unsigned)s >> 4] >> (((unsigned)s & 15u) << 1)) & 3;
                b = (pnt[(unsigned)d >> 4] >> (((unsigned)d & 15u) << 1)) & 3;
            } else {
                a = node_type[s];
                b = node_type[d];
            }
            float vv = lw[edge_type[ee] * 9 + a * 3 + b];
            int bb = edge_batch[ee];
            if (bb != cur) {
                if (cur >= 0) atomicAdd(&out[cur], acc);
                cur = bb; acc = 0.0f;
            }
            acc += vv;
        }
        if (cur >= 0) atomicAdd(&out[cur], acc);
    }
}

extern "C" void kernel_launch(void* const* d_in, const int* in_sizes, int n_in,
                              void* d_out, int out_size, void* d_ws, size_t ws_size,
                              hipStream_t stream) {
    const int*   node_type  = (const int*)d_in[0];
    const int*   edge_type  = (const int*)d_in[1];
    const int*   edge_index = (const int*)d_in[2];   // [2, E]: src then dst
    const int*   edge_batch = (const int*)d_in[3];
    const float* w          = (const float*)d_in[4];
    float* out = (float*)d_out;

    long N = in_sizes[0];
    long E = in_sizes[1];

    // d_out is poisoned once and never re-poisoned between replays; we
    // accumulate with atomics, so zero it at the start of every launch.
    zero_kernel<<<(out_size + 255) / 256, 256, 0, stream>>>(out, out_size);

    long waves_total = (E + 255) / 256;
    long threads     = waves_total * 64;
    int  blocks      = (int)((threads + 255) / 256);

    int nwords = (int)((N + 15) / 16);
    bool have_ws = (ws_size >= (size_t)nwords * 4);

    if (have_ws) {
        unsigned int* pnt = (unsigned int*)d_ws;
        pack_nt_kernel<<<(nwords + 255) / 256, 256, 0, stream>>>(node_type, pnt, nwords, (int)N);
        edge_score_kernel<true><<<blocks, 256, 0, stream>>>(
            pnt, node_type, edge_type, edge_index, edge_index + E, edge_batch, w, out,
            E, waves_total);
    } else {
        edge_score_kernel<false><<<blocks, 256, 0, stream>>>(
            nullptr, node_type, edge_type, edge_index, edge_index + E, edge_batch, w, out,
            E, waves_total);
    }
}